// Round 3
// baseline (30.934 us; speedup 1.0000x reference)
//
#include <hip/hip_runtime.h>
#include <math.h>

// Problem constants (match reference)
constexpr int   BB    = 32;
constexpr int   NF    = 500;
constexpr int   FS    = 240;
constexpr int   TT    = NF * FS;     // 120000
constexpr int   HH    = 8;
constexpr float ALPHA = 0.1f;

constexpr int SPT = 8;               // samples per thread (240 % 8 == 0)
constexpr int BLK = 256;

__device__ __forceinline__ float sin_rev(float fr) {
    // fr in [-0.5, 0.5] revolutions; v_sin_f32: D = sin(S0 * 2pi)
#if __has_builtin(__builtin_amdgcn_sinf)
    return __builtin_amdgcn_sinf(fr);
#else
    return __sinf(fr * 6.28318530717958647692f);
#endif
}

__device__ __forceinline__ float tanh_fast(float x) {
    // tanh(x) = 1 - 2/(e^{2x}+1); exp->inf saturates to +1, exp->0 gives -1.
    const float e = __expf(2.0f * x);
#if __has_builtin(__builtin_amdgcn_rcpf)
    const float r = __builtin_amdgcn_rcpf(e + 1.0f);
#else
    const float r = 1.0f / (e + 1.0f);
#endif
    return fmaf(-2.0f, r, 1.0f);
}

// ---------------------------------------------------------------------------
// Fused kernel, prefetch-first schedule:
//   1) every thread issues its 16 float4 noise loads (independent of scan)
//   2) wave 0 runs the f64 frame-phase scan into LDS
//   3) barrier -> compute (loads have landed under the scan/latency)
// ---------------------------------------------------------------------------
__global__ __launch_bounds__(BLK) void synth_fused(const float* __restrict__ f0s,
                                                   const float* __restrict__ phi,
                                                   const float* __restrict__ amp,
                                                   const float* __restrict__ noise,
                                                   float* __restrict__ out) {
    const int b   = blockIdx.y;
    const int tid = threadIdx.x;

    __shared__ float2 sfr[NF];   // {frac(prefix_rev) at frame start, dphi_rev}

    // ---- addresses + prefetch (before scan/barrier) ----
    const int t     = (blockIdx.x * BLK + tid) * SPT;
    const bool valid = (t < TT);
    const int tc    = valid ? t : (TT - SPT);      // clamp tail (same cachelines)
    const int f     = tc / FS;
    const int j     = tc - f * FS;                 // multiple of 8, within frame
    const size_t base = (size_t)b * TT + tc;

    float4 n0[HH], n1[HH];
#pragma unroll
    for (int h = 0; h < HH; ++h) {
        const float4* p = reinterpret_cast<const float4*>(
            noise + (size_t)h * (BB * (size_t)TT) + base);
        n0[h] = p[0];
        n1[h] = p[1];
    }

    // ---- wave 0: frame-level phase prefix scan (f64, revolutions) ----
    if (tid < 64) {
        const int lane = tid;
        const float  TWO_PI_F = 6.28318530717958647692f;
        const double INV_2PI  = 0.15915494309189533576;

        double d[8];
        double sum = 0.0;
#pragma unroll
        for (int i = 0; i < 8; ++i) {
            const int fr = lane * 8 + i;
            const float f0   = (fr < NF) ? f0s[b * NF + fr] : 0.0f;
            const float dphi = (TWO_PI_F * f0) / 24000.0f;   // f32, matches np op order
            d[i] = (double)dphi * INV_2PI;                   // revolutions/sample
            sum += d[i];
        }

        const double mine = sum * 240.0;
        double run = mine;
        for (int delta = 1; delta < 64; delta <<= 1) {
            const double o = __shfl_up(run, delta, 64);
            if (lane >= delta) run += o;
        }
        double acc = run - mine;   // exclusive prefix at this lane's first frame

#pragma unroll
        for (int i = 0; i < 8; ++i) {
            const int fr = lane * 8 + i;
            if (fr < NF) {
                const double fx = acc - rint(acc);
                sfr[fr] = make_float2((float)fx, (float)d[i]);
            }
            acc += d[i] * 240.0;
        }
    }
    __syncthreads();

    // ---- per-thread synth of 8 consecutive samples ----
    const float2 fd = sfr[f];
    const float  dr = fd.y;
    const bool   voiced = (dr > 0.0f);

    float cs[SPT];
    cs[0] = fd.x + (float)(j + 1) * dr;       // inclusive cumsum semantics
#pragma unroll
    for (int e = 1; e < SPT; ++e) cs[e] = cs[e - 1] + dr;

    const float INV2PIf = 0.15915494309189533576f;

    float sdot[SPT], ndot[SPT], kcs[SPT];
#pragma unroll
    for (int e = 0; e < SPT; ++e) { sdot[e] = 0.f; ndot[e] = 0.f; kcs[e] = 0.f; }

#pragma unroll
    for (int h = 0; h < HH; ++h) {
        const float a  = amp[h];
        const float ph = phi[h] * INV2PIf;

        ndot[0] = fmaf(a, n0[h].x, ndot[0]);
        ndot[1] = fmaf(a, n0[h].y, ndot[1]);
        ndot[2] = fmaf(a, n0[h].z, ndot[2]);
        ndot[3] = fmaf(a, n0[h].w, ndot[3]);
        ndot[4] = fmaf(a, n1[h].x, ndot[4]);
        ndot[5] = fmaf(a, n1[h].y, ndot[5]);
        ndot[6] = fmaf(a, n1[h].z, ndot[6]);
        ndot[7] = fmaf(a, n1[h].w, ndot[7]);

#pragma unroll
        for (int e = 0; e < SPT; ++e) {
            kcs[e] += cs[e];                  // k = (h+1) * cs
            const float r  = kcs[e] + ph;
            const float fx = r - rintf(r);    // reduce to [-0.5, 0.5] rev
            sdot[e] = fmaf(a, sin_rev(fx), sdot[e]);
        }
    }

    const float a8 = amp[HH];
    const float UV = (float)(0.1 / (3.0 * 0.003));   // ALPHA / (3*SIGMA)

    float tmp[SPT];
#pragma unroll
    for (int e = 0; e < SPT; ++e) {
        const float x = voiced ? fmaf(ALPHA, sdot[e], ndot[e]) : UV * ndot[e];
        tmp[e] = tanh_fast(x + a8);
    }

    if (valid) {
        float4* ov = reinterpret_cast<float4*>(out + base);
        ov[0] = make_float4(tmp[0], tmp[1], tmp[2], tmp[3]);
        ov[1] = make_float4(tmp[4], tmp[5], tmp[6], tmp[7]);
    }
}

// ---------------------------------------------------------------------------
extern "C" void kernel_launch(void* const* d_in, const int* in_sizes, int n_in,
                              void* d_out, int out_size, void* d_ws, size_t ws_size,
                              hipStream_t stream) {
    const float* f0s   = (const float*)d_in[0];   // [32, 500]
    const float* phi   = (const float*)d_in[1];   // [8]
    const float* amp   = (const float*)d_in[2];   // [9]
    const float* noise = (const float*)d_in[3];   // [8, 32, 120000]
    float* out = (float*)d_out;                   // [32, 120000]

    const int blocks_x = (TT / SPT + BLK - 1) / BLK;   // 59
    dim3 grid(blocks_x, BB);
    synth_fused<<<grid, BLK, 0, stream>>>(f0s, phi, amp, noise, out);
}